// Round 13
// baseline (552.901 us; speedup 1.0000x reference)
//
#include <hip/hip_runtime.h>
#include <hip/hip_bf16.h>
#include <hip/hip_cooperative_groups.h>

namespace cg = cooperative_groups;

typedef __hip_bfloat16 bf16;
typedef short s8v __attribute__((ext_vector_type(8)));   // 8 bf16 (4 VGPRs)
typedef float f32x4 __attribute__((ext_vector_type(4))); // MFMA accumulator

__device__ __forceinline__ unsigned short f2bf_bits(float x) {
    union { bf16 h; unsigned short u; } v; v.h = __float2bfloat16(x); return v.u;
}
__device__ __forceinline__ float bfbits2f(unsigned short u) {
    union { unsigned u32; float f; } v; v.u32 = ((unsigned)u) << 16; return v.f;
}

// async global->LDS, 16B per lane; LDS dest must be uniform base + lane*16
template<typename T>
__device__ __forceinline__ void gload_lds16(const T* g, T* l) {
    __builtin_amdgcn_global_load_lds(
        (const __attribute__((address_space(1))) unsigned int*)g,
        (__attribute__((address_space(3))) unsigned int*)l, 16, 0, 0);
}

__device__ __forceinline__ uint4 load8(const bf16* p) { return *(const uint4*)p; }

__device__ __forceinline__ void tr1(const float* W, bf16* Wt, int idx, int K, int N) {
    int nn = idx / K, k = idx - nn * K;
    Wt[idx] = __float2bfloat16(W[(size_t)k * N + nn]);
}

// ---------------- cooperative build: prep + hist + scan + scatter in ONE dispatch ----
// 256 blocks x 1024 threads (1 block/CU -> co-resident). Phases separated by grid.sync().
__global__ __launch_bounds__(1024) void build_kernel(
        const float* __restrict__ x, bf16* __restrict__ xb, int nc4,
        const float* __restrict__ W0, const float* __restrict__ W1,
        const float* __restrict__ W2, bf16* __restrict__ wt0,
        bf16* __restrict__ wt1, bf16* __restrict__ wt2,
        const int* __restrict__ esrc, const int* __restrict__ edst,
        int* __restrict__ cursor, int* __restrict__ row_ptr,
        int* __restrict__ col_src, int* __restrict__ blocksums,
        int E, int n, int nb) {
    cg::grid_group grid = cg::this_grid();
    __shared__ int wsum[16];
    __shared__ int woff[16];
    int tid = threadIdx.x;
    int lane = tid & 63, wid = tid >> 6;
    int gsize = gridDim.x * blockDim.x;
    int gtid = blockIdx.x * blockDim.x + tid;

    // ---- P0: x->bf16 convert, weight transposes, zero counts ----
    for (int i = gtid; i < nc4; i += gsize) {
        float4 f = *(const float4*)(x + (size_t)i * 4);
        union { uint2 u; unsigned short us[4]; } cv;
        cv.us[0] = f2bf_bits(f.x); cv.us[1] = f2bf_bits(f.y);
        cv.us[2] = f2bf_bits(f.z); cv.us[3] = f2bf_bits(f.w);
        *(uint2*)(xb + (size_t)i * 4) = cv.u;
    }
    for (int i = gtid; i < 114688; i += gsize) {
        int i2 = i;
        if (i2 < 32768) tr1(W0, wt0, i2, 128, 256);
        else if ((i2 -= 32768) < 65536) tr1(W1, wt1, i2, 256, 256);
        else tr1(W2, wt2, i2 - 65536, 256, 64);
    }
    for (int i = gtid; i < n; i += gsize) cursor[i] = 0;
    grid.sync();

    // ---- P1: histogram of dst ----
    for (int i = gtid; i < E; i += gsize) {
        int d = edst[i];
        if ((unsigned)d < (unsigned)n) atomicAdd(&cursor[d], 1);
    }
    grid.sync();

    // ---- P2a: per-block exclusive scan of counts[i]+1 over 1024-chunks ----
    if (blockIdx.x < (unsigned)nb) {
        int i = blockIdx.x * 1024 + tid;
        int v = (i < n) ? cursor[i] + 1 : 0;   // +1 = self-loop
        int incl = v;
        #pragma unroll
        for (int d = 1; d < 64; d <<= 1) {
            int t = __shfl_up(incl, d, 64);
            if (lane >= d) incl += t;
        }
        if (lane == 63) wsum[wid] = incl;
        __syncthreads();
        if (wid == 0) {
            int wv = (lane < 16) ? wsum[lane] : 0;
            int wincl = wv;
            #pragma unroll
            for (int d = 1; d < 16; d <<= 1) {
                int t = __shfl_up(wincl, d, 64);
                if (lane >= d) wincl += t;
            }
            if (lane < 16) woff[lane] = wincl - wv;
        }
        __syncthreads();
        if (i < n) row_ptr[i] = woff[wid] + incl - v;
        if (tid == 1023) blocksums[blockIdx.x] = woff[15] + wsum[15];
    }
    grid.sync();

    // ---- P2b: apply block-base offsets (each wave re-scans <=64 block sums) ----
    if (blockIdx.x < (unsigned)nb) {
        int v = (lane < nb) ? blocksums[lane] : 0;
        int incl = v;
        #pragma unroll
        for (int d = 1; d < 64; d <<= 1) {
            int t = __shfl_up(incl, d, 64);
            if (lane >= d) incl += t;
        }
        int base = __shfl(incl - v, blockIdx.x, 64);
        int total = __shfl(incl, nb - 1, 64);
        int i = blockIdx.x * 1024 + tid;
        if (i < n) {
            int val = row_ptr[i] + base;
            row_ptr[i] = val;
            cursor[i] = val;
        }
        if (blockIdx.x == 0 && tid == 0) row_ptr[n] = total;
    }
    grid.sync();

    // ---- P3: scatter (edges + self-loops) ----
    for (int i = gtid; i < E + n; i += gsize) {
        if (i < E) {
            int d = edst[i];
            if ((unsigned)d >= (unsigned)n) continue;
            int s = esrc[i];
            if ((unsigned)s >= (unsigned)n) s = d;
            int pos = atomicAdd(&cursor[d], 1);
            col_src[pos] = s;
        } else {
            int v = i - E;
            int pos = atomicAdd(&cursor[v], 1);
            col_src[pos] = v;  // self-loop
        }
    }
}

// ---------------- 128x128 MFMA GEMM + fused alpha epilogue (direct store) ----------------
__global__ __launch_bounds__(256) void gemm128_kernel(
        const bf16* __restrict__ A, const bf16* __restrict__ Wt, bf16* __restrict__ C,
        const float* __restrict__ a_src, const float* __restrict__ a_dst,
        float* __restrict__ asb, float* __restrict__ adb,
        int M, int K, int N, int H) {
    __shared__ __align__(16) bf16 As[128 * 64];
    __shared__ __align__(16) bf16 Bs[128 * 64];
    int tid = threadIdx.x;
    int w = tid >> 6, l = tid & 63;
    int lm = l & 15, quad = l >> 4;
    int m0 = blockIdx.x * 128, n0 = blockIdx.y * 128;
    int wr = (w >> 1) * 64, wc = (w & 1) * 64;
    int srow = w * 32 + (l >> 3);
    int schunk = l & 7;
    f32x4 acc[4][4] = {};
    for (int kt = 0; kt < K; kt += 64) {
        #pragma unroll
        for (int j = 0; j < 4; ++j) {
            int row = srow + j * 8;
            int g = schunk ^ (row & 7);
            int m = m0 + row; if (m >= M) m = M - 1;  // clamp: dup rows, never stored
            gload_lds16(A + (size_t)m * K + kt + g * 8, As + row * 64 + schunk * 8);
            gload_lds16(Wt + (size_t)(n0 + row) * K + kt + g * 8, Bs + row * 64 + schunk * 8);
        }
        __syncthreads();
        #pragma unroll
        for (int ks = 0; ks < 2; ++ks) {
            s8v a[4], b[4];
            #pragma unroll
            for (int mi = 0; mi < 4; ++mi) {
                int row = wr + mi * 16 + lm;
                int c = (ks * 4 + quad) ^ (row & 7);
                a[mi] = *(const s8v*)(As + row * 64 + c * 8);
            }
            #pragma unroll
            for (int ni = 0; ni < 4; ++ni) {
                int row = wc + ni * 16 + lm;
                int c = (ks * 4 + quad) ^ (row & 7);
                b[ni] = *(const s8v*)(Bs + row * 64 + c * 8);
            }
            #pragma unroll
            for (int mi = 0; mi < 4; ++mi)
                #pragma unroll
                for (int ni = 0; ni < 4; ++ni)
                    acc[mi][ni] = __builtin_amdgcn_mfma_f32_16x16x32_bf16(
                        a[mi], b[ni], acc[mi][ni], 0, 0, 0);
        }
        __syncthreads();
    }
    int head = (n0 + wc) >> 6;
    float a_s[4], a_d[4];
    #pragma unroll
    for (int ni = 0; ni < 4; ++ni) {
        int col = n0 + wc + ni * 16 + lm;
        a_s[ni] = a_src[col];
        a_d[ni] = a_dst[col];
    }
    #pragma unroll
    for (int mi = 0; mi < 4; ++mi) {
        #pragma unroll
        for (int reg = 0; reg < 4; ++reg) {
            int m = m0 + wr + mi * 16 + quad * 4 + reg;
            float ps = 0.f, pd = 0.f;
            #pragma unroll
            for (int ni = 0; ni < 4; ++ni) {
                float v = acc[mi][ni][reg];
                ps += v * a_s[ni];
                pd += v * a_d[ni];
                if (m < M)
                    C[(size_t)m * N + n0 + wc + ni * 16 + lm] = __float2bfloat16(v);
            }
            #pragma unroll
            for (int d = 1; d < 16; d <<= 1) {
                ps += __shfl_xor(ps, d, 64);
                pd += __shfl_xor(pd, d, 64);
            }
            if (lm == 0 && m < M) {
                asb[(size_t)m * H + head] = ps;
                adb[(size_t)m * H + head] = pd;
            }
        }
    }
}

// ---------------- 64x64 MFMA GEMM + fused alpha (layer 2, N=64, H=1, direct store) ----
__global__ __launch_bounds__(256) void gemm64_kernel(
        const bf16* __restrict__ A, const bf16* __restrict__ Wt, bf16* __restrict__ C,
        const float* __restrict__ a_src, const float* __restrict__ a_dst,
        float* __restrict__ asb, float* __restrict__ adb,
        int M, int K, int N) {
    __shared__ __align__(16) bf16 As[64][72];
    __shared__ __align__(16) bf16 Bs[64][72];
    int tid = threadIdx.x;
    int m0 = blockIdx.x * 64;
    int w = tid >> 6;
    int l = tid & 63;
    int lm = l & 15;
    int quad = l >> 4;
    int r = tid >> 2;
    int kb = (tid & 3) * 8;
    f32x4 acc[4] = {};
    int mstage = m0 + r;
    for (int kt = 0; kt < K; kt += 64) {
        #pragma unroll
        for (int c = 0; c < 2; ++c) {
            int kk = kb + c * 32;
            uint4 av = (mstage < M) ? load8(&A[(size_t)mstage * K + kt + kk])
                                    : make_uint4(0, 0, 0, 0);
            *(uint4*)&As[r][kk] = av;
            *(uint4*)&Bs[r][kk] = load8(&Wt[(size_t)r * K + kt + kk]);
        }
        __syncthreads();
        #pragma unroll
        for (int ks = 0; ks < 2; ++ks) {
            s8v a = *(const s8v*)&As[w * 16 + lm][ks * 32 + quad * 8];
            #pragma unroll
            for (int nb = 0; nb < 4; ++nb) {
                s8v b = *(const s8v*)&Bs[nb * 16 + lm][ks * 32 + quad * 8];
                acc[nb] = __builtin_amdgcn_mfma_f32_16x16x32_bf16(a, b, acc[nb], 0, 0, 0);
            }
        }
        __syncthreads();
    }
    float a_s[4], a_d[4];
    #pragma unroll
    for (int nb = 0; nb < 4; ++nb) {
        a_s[nb] = a_src[nb * 16 + lm];
        a_d[nb] = a_dst[nb * 16 + lm];
    }
    #pragma unroll
    for (int reg = 0; reg < 4; ++reg) {
        int m = m0 + w * 16 + quad * 4 + reg;
        float ps = 0.f, pd = 0.f;
        #pragma unroll
        for (int nb = 0; nb < 4; ++nb) {
            float v = acc[nb][reg];
            ps += v * a_s[nb];
            pd += v * a_d[nb];
            if (m < M)
                C[(size_t)m * N + nb * 16 + lm] = __float2bfloat16(v);
        }
        #pragma unroll
        for (int d = 1; d < 16; d <<= 1) {
            ps += __shfl_xor(ps, d, 64);
            pd += __shfl_xor(pd, d, 64);
        }
        if (lm == 0 && m < M) {
            asb[m] = ps;
            adb[m] = pd;
        }
    }
}

// ---------------- 4-head edge softmax + aggregation (r6 form: measured best) --------
__global__ __launch_bounds__(256) void agg4_kernel(
        const bf16* __restrict__ hbuf,
        const float* __restrict__ asb, const float* __restrict__ adb,
        const int* __restrict__ row_ptr, const int* __restrict__ col_src,
        const float* __restrict__ bias,
        bf16* __restrict__ outp, int n) {
    int lane = threadIdx.x & 63;
    int node = blockIdx.x * 4 + (threadIdx.x >> 6);
    if (node >= n) return;
    const int c0 = lane * 4;
    const int head = c0 >> 6;
    int start = row_ptr[node], end = row_ptr[node + 1];
    float adn = adb[(size_t)node * 4 + head];
    float acc[4] = {};
    float denom = 0.f;

    auto edge_w = [&](int s) -> float {
        float x = asb[(size_t)s * 4 + head] + adn;
        x = (x > 0.f) ? x : 0.2f * x;            // leaky_relu 0.2
        return __expf(fminf(x, 30.f));
    };
    auto loadH = [&](int s, float* o) {
        union { uint2 u; unsigned short us[4]; } cv;
        cv.u = *(const uint2*)(hbuf + (size_t)s * 256 + c0);
        #pragma unroll
        for (int v = 0; v < 4; ++v) o[v] = bfbits2f(cv.us[v]);
    };

    int e = start;
    for (; e + 4 <= end; e += 4) {
        int s0 = col_src[e], s1 = col_src[e + 1], s2 = col_src[e + 2], s3 = col_src[e + 3];
        float h0[4], h1[4], h2[4], h3[4];
        loadH(s0, h0); loadH(s1, h1); loadH(s2, h2); loadH(s3, h3);
        float w0 = edge_w(s0), w1 = edge_w(s1), w2 = edge_w(s2), w3 = edge_w(s3);
        denom += (w0 + w1) + (w2 + w3);
        #pragma unroll
        for (int v = 0; v < 4; ++v)
            acc[v] += w0 * h0[v] + w1 * h1[v] + w2 * h2[v] + w3 * h3[v];
    }
    for (; e < end; ++e) {
        int s = col_src[e];
        float hv[4];
        loadH(s, hv);
        float w = edge_w(s);
        denom += w;
        #pragma unroll
        for (int v = 0; v < 4; ++v) acc[v] += w * hv[v];
    }
    float inv = 1.f / (denom + 1e-16f);
    union { uint2 u; unsigned short us[4]; } cv;
    #pragma unroll
    for (int v = 0; v < 4; ++v) {
        float o = acc[v] * inv + bias[c0 + v];
        o = (o > 0.f) ? o : (__expf(o) - 1.f);   // ELU
        cv.us[v] = f2bf_bits(o);
    }
    *(uint2*)(outp + (size_t)node * 256 + c0) = cv.u;
}

// ---------------- layer-2 aggregation: 2 nodes per wave (half-wave, VEC=2) ----------
__global__ __launch_bounds__(256) void agg2_kernel(
        const bf16* __restrict__ hbuf,
        const float* __restrict__ asb, const float* __restrict__ adb,
        const int* __restrict__ row_ptr, const int* __restrict__ col_src,
        const float* __restrict__ bias,
        float* __restrict__ outp, int n) {
    int tid = threadIdx.x;
    int l32 = tid & 31;
    int node = blockIdx.x * 8 + (tid >> 5);   // 8 nodes per 256-thread block
    if (node >= n) return;
    const int c0 = l32 * 2;
    int start = row_ptr[node], end = row_ptr[node + 1];
    float adn = adb[node];
    float acc0 = 0.f, acc1 = 0.f, denom = 0.f;

    auto edge_w = [&](int s) -> float {
        float x = asb[s] + adn;
        x = (x > 0.f) ? x : 0.2f * x;
        return __expf(fminf(x, 30.f));
    };
    auto loadH2 = [&](int s, float& o0, float& o1) {
        unsigned u = *(const unsigned*)(hbuf + (size_t)s * 64 + c0);
        o0 = bfbits2f((unsigned short)(u & 0xffffu));
        o1 = bfbits2f((unsigned short)(u >> 16));
    };

    int e = start;
    for (; e + 4 <= end; e += 4) {
        int s0 = col_src[e], s1 = col_src[e + 1], s2 = col_src[e + 2], s3 = col_src[e + 3];
        float a0, b0, a1, b1, a2, b2, a3, b3;
        loadH2(s0, a0, b0); loadH2(s1, a1, b1); loadH2(s2, a2, b2); loadH2(s3, a3, b3);
        float w0 = edge_w(s0), w1 = edge_w(s1), w2 = edge_w(s2), w3 = edge_w(s3);
        denom += (w0 + w1) + (w2 + w3);
        acc0 += w0 * a0 + w1 * a1 + w2 * a2 + w3 * a3;
        acc1 += w0 * b0 + w1 * b1 + w2 * b2 + w3 * b3;
    }
    for (; e < end; ++e) {
        int s = col_src[e];
        float a, b;
        loadH2(s, a, b);
        float w = edge_w(s);
        denom += w;
        acc0 += w * a;
        acc1 += w * b;
    }
    float inv = 1.f / (denom + 1e-16f);
    float2 o;
    o.x = acc0 * inv + bias[c0];
    o.y = acc1 * inv + bias[c0 + 1];
    *(float2*)(outp + (size_t)node * 64 + c0) = o;
}

extern "C" void kernel_launch(void* const* d_in, const int* in_sizes, int n_in,
                              void* d_out, int out_size, void* d_ws, size_t ws_size,
                              hipStream_t stream) {
    const float* x   = (const float*)d_in[0];
    const int*   ei  = (const int*)d_in[1];
    const float* W0  = (const float*)d_in[2];
    const float* as0 = (const float*)d_in[3];
    const float* ad0 = (const float*)d_in[4];
    const float* b0  = (const float*)d_in[5];
    const float* W1  = (const float*)d_in[6];
    const float* as1 = (const float*)d_in[7];
    const float* ad1 = (const float*)d_in[8];
    const float* b1  = (const float*)d_in[9];
    const float* W2  = (const float*)d_in[10];
    const float* as2 = (const float*)d_in[11];
    const float* ad2 = (const float*)d_in[12];
    const float* b2  = (const float*)d_in[13];
    float* out = (float*)d_out;

    const int n = in_sizes[0] / 128;   // 50000
    const int E = in_sizes[1] / 2;     // 800000
    const int* esrc = ei;
    const int* edst = ei + E;

    // workspace (~58 MB)
    char* ws = (char*)d_ws;
    bf16* hb0 = (bf16*)ws;                                   // n*256 bf16
    bf16* hb1 = hb0 + (size_t)n * 256;                       // n*256 bf16
    bf16* xb  = hb1 + (size_t)n * 256;                       // n*128 bf16
    bf16* wt0 = xb + (size_t)n * 128;                        // 256*128
    bf16* wt1 = wt0 + 128 * 256;                             // 256*256
    bf16* wt2 = wt1 + 256 * 256;                             // 64*256
    float* asb = (float*)(wt2 + 256 * 64);                   // n*4 fp32
    float* adb = asb + (size_t)n * 4;                        // n*4 fp32
    int* row_ptr = (int*)(adb + (size_t)n * 4);              // n+1 (+pad)
    int* cursor  = row_ptr + (n + 64);                       // n  (doubles as counts)
    int* col_src = cursor + n;                               // E+n
    int* blocksums = col_src + (E + n + 64);                 // <=256

    int nb = (n + 1023) / 1024;        // 49 scan blocks (<= 64 for in-wave rescan)
    int nc4 = n * 128 / 4;             // x convert quads

    // ---- cooperative build: prep + CSR in ONE dispatch ----
    {
        void* args[] = {
            (void*)&x, (void*)&xb, (void*)&nc4,
            (void*)&W0, (void*)&W1, (void*)&W2,
            (void*)&wt0, (void*)&wt1, (void*)&wt2,
            (void*)&esrc, (void*)&edst,
            (void*)&cursor, (void*)&row_ptr, (void*)&col_src, (void*)&blocksums,
            (void*)&E, (void*)&n, (void*)&nb
        };
        hipLaunchCooperativeKernel((void*)build_kernel, dim3(256), dim3(1024),
                                   args, 0, stream);
    }

    dim3 blk(256);
    int mg128 = (n + 127) / 128;
    int mg64  = (n + 63) / 64;
    int ag4 = (n + 3) / 4;   // 4 nodes/block (wave per node)
    int ag2 = (n + 7) / 8;   // 8 nodes/block (half-wave per node)

    // ---- layer 0: x[n,128] @ W0[128,256] ----
    gemm128_kernel<<<dim3(mg128, 2), blk, 0, stream>>>(xb, wt0, hb0, as0, ad0,
                                                       asb, adb, n, 128, 256, 4);
    agg4_kernel<<<ag4, blk, 0, stream>>>(hb0, asb, adb, row_ptr, col_src, b0, hb1, n);
    // ---- layer 1: h[n,256] @ W1[256,256] ----
    gemm128_kernel<<<dim3(mg128, 2), blk, 0, stream>>>(hb1, wt1, hb0, as1, ad1,
                                                       asb, adb, n, 256, 256, 4);
    agg4_kernel<<<ag4, blk, 0, stream>>>(hb0, asb, adb, row_ptr, col_src, b1, hb1, n);
    // ---- layer 2: h[n,256] @ W2[256,64], heads=1, no ELU, fp32 out ----
    gemm64_kernel<<<dim3(mg64, 1), blk, 0, stream>>>(hb1, wt2, hb0, as2, ad2,
                                                     asb, adb, n, 256, 64);
    agg2_kernel<<<ag2, blk, 0, stream>>>(hb0, asb, adb, row_ptr, col_src, b2, out, n);
}

// Round 14
// 450.808 us; speedup vs baseline: 1.2265x; 1.2265x over previous
//
#include <hip/hip_runtime.h>
#include <hip/hip_bf16.h>

typedef __hip_bfloat16 bf16;
typedef short s8v __attribute__((ext_vector_type(8)));   // 8 bf16 (4 VGPRs)
typedef float f32x4 __attribute__((ext_vector_type(4))); // MFMA accumulator

__device__ __forceinline__ unsigned short f2bf_bits(float x) {
    union { bf16 h; unsigned short u; } v; v.h = __float2bfloat16(x); return v.u;
}
__device__ __forceinline__ float bfbits2f(unsigned short u) {
    union { unsigned u32; float f; } v; v.u32 = ((unsigned)u) << 16; return v.f;
}

// async global->LDS, 16B per lane; LDS dest must be uniform base + lane*16
template<typename T>
__device__ __forceinline__ void gload_lds16(const T* g, T* l) {
    __builtin_amdgcn_global_load_lds(
        (const __attribute__((address_space(1))) unsigned int*)g,
        (__attribute__((address_space(3))) unsigned int*)l, 16, 0, 0);
}

__device__ __forceinline__ uint4 load8(const bf16* p) { return *(const uint4*)p; }

// ---------------- mega-prep: x->bf16 + 3 weight transposes + zero cursor ----------------
__device__ __forceinline__ void tr1(const float* W, bf16* Wt, int idx, int K, int N) {
    int nn = idx / K, k = idx - nn * K;
    Wt[idx] = __float2bfloat16(W[(size_t)k * N + nn]);
}
__global__ void prep_kernel(const float* __restrict__ x, bf16* __restrict__ xb, int nc4,
                            const float* __restrict__ W0, const float* __restrict__ W1,
                            const float* __restrict__ W2, bf16* __restrict__ wt0,
                            bf16* __restrict__ wt1, bf16* __restrict__ wt2,
                            int* __restrict__ cursor, int n) {
    int idx = blockIdx.x * blockDim.x + threadIdx.x;
    if (idx < nc4) {
        float4 f = *(const float4*)(x + (size_t)idx * 4);
        union { uint2 u; unsigned short us[4]; } cv;
        cv.us[0] = f2bf_bits(f.x); cv.us[1] = f2bf_bits(f.y);
        cv.us[2] = f2bf_bits(f.z); cv.us[3] = f2bf_bits(f.w);
        *(uint2*)(xb + (size_t)idx * 4) = cv.u;
        return;
    }
    int i2 = idx - nc4;
    if (i2 < 32768) { tr1(W0, wt0, i2, 128, 256); return; }
    i2 -= 32768;
    if (i2 < 65536) { tr1(W1, wt1, i2, 256, 256); return; }
    i2 -= 65536;
    if (i2 < 16384) { tr1(W2, wt2, i2, 256, 64); return; }
    i2 -= 16384;
    if (i2 < n) cursor[i2] = 0;
}

// ---------------- CSR build ----------------
__global__ void hist_kernel(const int* __restrict__ dst, int* counts, int E, int n) {
    int i = blockIdx.x * blockDim.x + threadIdx.x;
    if (i < E) {
        int d = dst[i];
        if ((unsigned)d < (unsigned)n) atomicAdd(&counts[d], 1);
    }
}

// hierarchical scan, phase 1: per-block (1024) local exclusive scan of counts[i]+1
__global__ __launch_bounds__(1024) void scan_phase1(
        const int* __restrict__ counts, int* __restrict__ excl_out,
        int* __restrict__ blocksums, int n) {
    __shared__ int wsum[16];
    __shared__ int woff[16];
    int tid = threadIdx.x, lane = tid & 63, wid = tid >> 6;
    int i = blockIdx.x * 1024 + tid;
    int v = (i < n) ? counts[i] + 1 : 0;   // +1 = self-loop
    int incl = v;
    #pragma unroll
    for (int d = 1; d < 64; d <<= 1) {
        int t = __shfl_up(incl, d, 64);
        if (lane >= d) incl += t;
    }
    if (lane == 63) wsum[wid] = incl;
    __syncthreads();
    if (wid == 0) {
        int wv = (lane < 16) ? wsum[lane] : 0;
        int wincl = wv;
        #pragma unroll
        for (int d = 1; d < 16; d <<= 1) {
            int t = __shfl_up(wincl, d, 64);
            if (lane >= d) wincl += t;
        }
        if (lane < 16) woff[lane] = wincl - wv;
    }
    __syncthreads();
    if (i < n) excl_out[i] = woff[wid] + incl - v;
    if (tid == 1023) blocksums[blockIdx.x] = woff[15] + wsum[15];
}

// phase 2: every wave redundantly scans the <=64 block sums; apply offsets
__global__ __launch_bounds__(1024) void scan_phase2(
        const int* __restrict__ blocksums, int* __restrict__ row_ptr,
        int* __restrict__ cursor, int nb, int n) {
    int tid = threadIdx.x, lane = tid & 63;
    int i = blockIdx.x * 1024 + tid;
    int v = (lane < nb) ? blocksums[lane] : 0;
    int incl = v;
    #pragma unroll
    for (int d = 1; d < 64; d <<= 1) {
        int t = __shfl_up(incl, d, 64);
        if (lane >= d) incl += t;
    }
    int excl_lane = incl - v;
    int base = __shfl(excl_lane, blockIdx.x, 64);
    int total = __shfl(incl, nb - 1, 64);
    if (i < n) {
        int val = row_ptr[i] + base;
        row_ptr[i] = val;
        cursor[i] = val;
    }
    if (blockIdx.x == 0 && tid == 0) row_ptr[n] = total;
}

__global__ void scatter_kernel(const int* __restrict__ src, const int* __restrict__ dst,
                               int* cursor, int* col_src, int E, int n) {
    int i = blockIdx.x * blockDim.x + threadIdx.x;
    if (i < E) {
        int d = dst[i];
        if ((unsigned)d >= (unsigned)n) return;
        int s = src[i];
        if ((unsigned)s >= (unsigned)n) s = d;
        int pos = atomicAdd(&cursor[d], 1);
        col_src[pos] = s;
    } else if (i < E + n) {
        int v = i - E;
        int pos = atomicAdd(&cursor[v], 1);
        col_src[pos] = v;  // self-loop
    }
}

// ---------------- 128x128 MFMA GEMM + fused alpha epilogue (direct store) ----------------
__global__ __launch_bounds__(256) void gemm128_kernel(
        const bf16* __restrict__ A, const bf16* __restrict__ Wt, bf16* __restrict__ C,
        const float* __restrict__ a_src, const float* __restrict__ a_dst,
        float* __restrict__ asb, float* __restrict__ adb,
        int M, int K, int N, int H) {
    __shared__ __align__(16) bf16 As[128 * 64];
    __shared__ __align__(16) bf16 Bs[128 * 64];
    int tid = threadIdx.x;
    int w = tid >> 6, l = tid & 63;
    int lm = l & 15, quad = l >> 4;
    int m0 = blockIdx.x * 128, n0 = blockIdx.y * 128;
    int wr = (w >> 1) * 64, wc = (w & 1) * 64;
    int srow = w * 32 + (l >> 3);
    int schunk = l & 7;
    f32x4 acc[4][4] = {};
    for (int kt = 0; kt < K; kt += 64) {
        #pragma unroll
        for (int j = 0; j < 4; ++j) {
            int row = srow + j * 8;
            int g = schunk ^ (row & 7);
            int m = m0 + row; if (m >= M) m = M - 1;  // clamp: dup rows, never stored
            gload_lds16(A + (size_t)m * K + kt + g * 8, As + row * 64 + schunk * 8);
            gload_lds16(Wt + (size_t)(n0 + row) * K + kt + g * 8, Bs + row * 64 + schunk * 8);
        }
        __syncthreads();
        #pragma unroll
        for (int ks = 0; ks < 2; ++ks) {
            s8v a[4], b[4];
            #pragma unroll
            for (int mi = 0; mi < 4; ++mi) {
                int row = wr + mi * 16 + lm;
                int c = (ks * 4 + quad) ^ (row & 7);
                a[mi] = *(const s8v*)(As + row * 64 + c * 8);
            }
            #pragma unroll
            for (int ni = 0; ni < 4; ++ni) {
                int row = wc + ni * 16 + lm;
                int c = (ks * 4 + quad) ^ (row & 7);
                b[ni] = *(const s8v*)(Bs + row * 64 + c * 8);
            }
            #pragma unroll
            for (int mi = 0; mi < 4; ++mi)
                #pragma unroll
                for (int ni = 0; ni < 4; ++ni)
                    acc[mi][ni] = __builtin_amdgcn_mfma_f32_16x16x32_bf16(
                        a[mi], b[ni], acc[mi][ni], 0, 0, 0);
        }
        __syncthreads();
    }
    int head = (n0 + wc) >> 6;
    float a_s[4], a_d[4];
    #pragma unroll
    for (int ni = 0; ni < 4; ++ni) {
        int col = n0 + wc + ni * 16 + lm;
        a_s[ni] = a_src[col];
        a_d[ni] = a_dst[col];
    }
    #pragma unroll
    for (int mi = 0; mi < 4; ++mi) {
        #pragma unroll
        for (int reg = 0; reg < 4; ++reg) {
            int m = m0 + wr + mi * 16 + quad * 4 + reg;
            float ps = 0.f, pd = 0.f;
            #pragma unroll
            for (int ni = 0; ni < 4; ++ni) {
                float v = acc[mi][ni][reg];
                ps += v * a_s[ni];
                pd += v * a_d[ni];
                if (m < M)
                    C[(size_t)m * N + n0 + wc + ni * 16 + lm] = __float2bfloat16(v);
            }
            #pragma unroll
            for (int d = 1; d < 16; d <<= 1) {
                ps += __shfl_xor(ps, d, 64);
                pd += __shfl_xor(pd, d, 64);
            }
            if (lm == 0 && m < M) {
                asb[(size_t)m * H + head] = ps;
                adb[(size_t)m * H + head] = pd;
            }
        }
    }
}

// ---------------- 64x64 MFMA GEMM + fused alpha (layer 2, N=64, H=1, direct store) ----
__global__ __launch_bounds__(256) void gemm64_kernel(
        const bf16* __restrict__ A, const bf16* __restrict__ Wt, bf16* __restrict__ C,
        const float* __restrict__ a_src, const float* __restrict__ a_dst,
        float* __restrict__ asb, float* __restrict__ adb,
        int M, int K, int N) {
    __shared__ __align__(16) bf16 As[64][72];
    __shared__ __align__(16) bf16 Bs[64][72];
    int tid = threadIdx.x;
    int m0 = blockIdx.x * 64;
    int w = tid >> 6;
    int l = tid & 63;
    int lm = l & 15;
    int quad = l >> 4;
    int r = tid >> 2;
    int kb = (tid & 3) * 8;
    f32x4 acc[4] = {};
    int mstage = m0 + r;
    for (int kt = 0; kt < K; kt += 64) {
        #pragma unroll
        for (int c = 0; c < 2; ++c) {
            int kk = kb + c * 32;
            uint4 av = (mstage < M) ? load8(&A[(size_t)mstage * K + kt + kk])
                                    : make_uint4(0, 0, 0, 0);
            *(uint4*)&As[r][kk] = av;
            *(uint4*)&Bs[r][kk] = load8(&Wt[(size_t)r * K + kt + kk]);
        }
        __syncthreads();
        #pragma unroll
        for (int ks = 0; ks < 2; ++ks) {
            s8v a = *(const s8v*)&As[w * 16 + lm][ks * 32 + quad * 8];
            #pragma unroll
            for (int nb = 0; nb < 4; ++nb) {
                s8v b = *(const s8v*)&Bs[nb * 16 + lm][ks * 32 + quad * 8];
                acc[nb] = __builtin_amdgcn_mfma_f32_16x16x32_bf16(a, b, acc[nb], 0, 0, 0);
            }
        }
        __syncthreads();
    }
    float a_s[4], a_d[4];
    #pragma unroll
    for (int nb = 0; nb < 4; ++nb) {
        a_s[nb] = a_src[nb * 16 + lm];
        a_d[nb] = a_dst[nb * 16 + lm];
    }
    #pragma unroll
    for (int reg = 0; reg < 4; ++reg) {
        int m = m0 + w * 16 + quad * 4 + reg;
        float ps = 0.f, pd = 0.f;
        #pragma unroll
        for (int nb = 0; nb < 4; ++nb) {
            float v = acc[nb][reg];
            ps += v * a_s[nb];
            pd += v * a_d[nb];
            if (m < M)
                C[(size_t)m * N + nb * 16 + lm] = __float2bfloat16(v);
        }
        #pragma unroll
        for (int d = 1; d < 16; d <<= 1) {
            ps += __shfl_xor(ps, d, 64);
            pd += __shfl_xor(pd, d, 64);
        }
        if (lm == 0 && m < M) {
            asb[m] = ps;
            adb[m] = pd;
        }
    }
}

// ---------------- 4-head agg, r12 form (wave per node) — CONTROL ----------------
__global__ __launch_bounds__(256) void agg4_kernel(
        const bf16* __restrict__ hbuf,
        const float* __restrict__ asb, const float* __restrict__ adb,
        const int* __restrict__ row_ptr, const int* __restrict__ col_src,
        const float* __restrict__ bias,
        bf16* __restrict__ outp, int n) {
    int lane = threadIdx.x & 63;
    int node = blockIdx.x * 4 + (threadIdx.x >> 6);
    if (node >= n) return;
    const int c0 = lane * 4;
    const int head = c0 >> 6;
    int start = row_ptr[node], end = row_ptr[node + 1];
    float adn = adb[(size_t)node * 4 + head];
    float acc[4] = {};
    float denom = 0.f;

    auto edge_w = [&](int s) -> float {
        float x = asb[(size_t)s * 4 + head] + adn;
        x = (x > 0.f) ? x : 0.2f * x;            // leaky_relu 0.2
        return __expf(fminf(x, 30.f));
    };
    auto loadH = [&](int s, float* o) {
        union { uint2 u; unsigned short us[4]; } cv;
        cv.u = *(const uint2*)(hbuf + (size_t)s * 256 + c0);
        #pragma unroll
        for (int v = 0; v < 4; ++v) o[v] = bfbits2f(cv.us[v]);
    };

    int e = start;
    for (; e + 4 <= end; e += 4) {
        int s0 = col_src[e], s1 = col_src[e + 1], s2 = col_src[e + 2], s3 = col_src[e + 3];
        float h0[4], h1[4], h2[4], h3[4];
        loadH(s0, h0); loadH(s1, h1); loadH(s2, h2); loadH(s3, h3);
        float w0 = edge_w(s0), w1 = edge_w(s1), w2 = edge_w(s2), w3 = edge_w(s3);
        denom += (w0 + w1) + (w2 + w3);
        #pragma unroll
        for (int v = 0; v < 4; ++v)
            acc[v] += w0 * h0[v] + w1 * h1[v] + w2 * h2[v] + w3 * h3[v];
    }
    for (; e < end; ++e) {
        int s = col_src[e];
        float hv[4];
        loadH(s, hv);
        float w = edge_w(s);
        denom += w;
        #pragma unroll
        for (int v = 0; v < 4; ++v) acc[v] += w * hv[v];
    }
    float inv = 1.f / (denom + 1e-16f);
    union { uint2 u; unsigned short us[4]; } cv;
    #pragma unroll
    for (int v = 0; v < 4; ++v) {
        float o = acc[v] * inv + bias[c0 + v];
        o = (o > 0.f) ? o : (__expf(o) - 1.f);   // ELU
        cv.us[v] = f2bf_bits(o);
    }
    *(uint2*)(outp + (size_t)node * 256 + c0) = cv.u;
}

// ---------------- 4-head agg, XCD-SLICED (experiment) ----------------
// Block handles ONE 32-channel slice for 32 nodes. slice = blockIdx&7 -> with
// round-robin block->XCD dispatch, XCD s only touches channels [32s,32s+32):
// working set 50000*64B = 3.2 MB, fits the 4 MB per-XCD L2 (vs 26 MB thrash).
// 8 lanes/node * 4ch/lane: same 8B loads and per-edge weight math as agg4;
// denominator recomputed per slice -> output bit-identical.
__global__ __launch_bounds__(256) void agg4s_kernel(
        const bf16* __restrict__ hbuf,
        const float* __restrict__ asb, const float* __restrict__ adb,
        const int* __restrict__ row_ptr, const int* __restrict__ col_src,
        const float* __restrict__ bias,
        bf16* __restrict__ outp, int n) {
    int slice = blockIdx.x & 7;
    int group = blockIdx.x >> 3;
    int tid = threadIdx.x;
    int node = group * 32 + (tid >> 3);
    if (node >= n) return;
    const int c0 = slice * 32 + (tid & 7) * 4;
    const int head = c0 >> 6;           // == slice>>1, uniform per block-slice
    int start = row_ptr[node], end = row_ptr[node + 1];
    float adn = adb[(size_t)node * 4 + head];
    float acc[4] = {};
    float denom = 0.f;

    auto edge_w = [&](int s) -> float {
        float x = asb[(size_t)s * 4 + head] + adn;
        x = (x > 0.f) ? x : 0.2f * x;
        return __expf(fminf(x, 30.f));
    };
    auto loadH = [&](int s, float* o) {
        union { uint2 u; unsigned short us[4]; } cv;
        cv.u = *(const uint2*)(hbuf + (size_t)s * 256 + c0);
        #pragma unroll
        for (int v = 0; v < 4; ++v) o[v] = bfbits2f(cv.us[v]);
    };

    int e = start;
    for (; e + 4 <= end; e += 4) {
        int s0 = col_src[e], s1 = col_src[e + 1], s2 = col_src[e + 2], s3 = col_src[e + 3];
        float h0[4], h1[4], h2[4], h3[4];
        loadH(s0, h0); loadH(s1, h1); loadH(s2, h2); loadH(s3, h3);
        float w0 = edge_w(s0), w1 = edge_w(s1), w2 = edge_w(s2), w3 = edge_w(s3);
        denom += (w0 + w1) + (w2 + w3);
        #pragma unroll
        for (int v = 0; v < 4; ++v)
            acc[v] += w0 * h0[v] + w1 * h1[v] + w2 * h2[v] + w3 * h3[v];
    }
    for (; e < end; ++e) {
        int s = col_src[e];
        float hv[4];
        loadH(s, hv);
        float w = edge_w(s);
        denom += w;
        #pragma unroll
        for (int v = 0; v < 4; ++v) acc[v] += w * hv[v];
    }
    float inv = 1.f / (denom + 1e-16f);
    union { uint2 u; unsigned short us[4]; } cv;
    #pragma unroll
    for (int v = 0; v < 4; ++v) {
        float o = acc[v] * inv + bias[c0 + v];
        o = (o > 0.f) ? o : (__expf(o) - 1.f);   // ELU
        cv.us[v] = f2bf_bits(o);
    }
    *(uint2*)(outp + (size_t)node * 256 + c0) = cv.u;
}

// ---------------- layer-2 aggregation: 2 nodes per wave (half-wave, VEC=2) ----------
__global__ __launch_bounds__(256) void agg2_kernel(
        const bf16* __restrict__ hbuf,
        const float* __restrict__ asb, const float* __restrict__ adb,
        const int* __restrict__ row_ptr, const int* __restrict__ col_src,
        const float* __restrict__ bias,
        float* __restrict__ outp, int n) {
    int tid = threadIdx.x;
    int l32 = tid & 31;
    int node = blockIdx.x * 8 + (tid >> 5);   // 8 nodes per 256-thread block
    if (node >= n) return;
    const int c0 = l32 * 2;
    int start = row_ptr[node], end = row_ptr[node + 1];
    float adn = adb[node];
    float acc0 = 0.f, acc1 = 0.f, denom = 0.f;

    auto edge_w = [&](int s) -> float {
        float x = asb[s] + adn;
        x = (x > 0.f) ? x : 0.2f * x;
        return __expf(fminf(x, 30.f));
    };
    auto loadH2 = [&](int s, float& o0, float& o1) {
        unsigned u = *(const unsigned*)(hbuf + (size_t)s * 64 + c0);
        o0 = bfbits2f((unsigned short)(u & 0xffffu));
        o1 = bfbits2f((unsigned short)(u >> 16));
    };

    int e = start;
    for (; e + 4 <= end; e += 4) {
        int s0 = col_src[e], s1 = col_src[e + 1], s2 = col_src[e + 2], s3 = col_src[e + 3];
        float a0, b0, a1, b1, a2, b2, a3, b3;
        loadH2(s0, a0, b0); loadH2(s1, a1, b1); loadH2(s2, a2, b2); loadH2(s3, a3, b3);
        float w0 = edge_w(s0), w1 = edge_w(s1), w2 = edge_w(s2), w3 = edge_w(s3);
        denom += (w0 + w1) + (w2 + w3);
        acc0 += w0 * a0 + w1 * a1 + w2 * a2 + w3 * a3;
        acc1 += w0 * b0 + w1 * b1 + w2 * b2 + w3 * b3;
    }
    for (; e < end; ++e) {
        int s = col_src[e];
        float a, b;
        loadH2(s, a, b);
        float w = edge_w(s);
        denom += w;
        acc0 += w * a;
        acc1 += w * b;
    }
    float inv = 1.f / (denom + 1e-16f);
    float2 o;
    o.x = acc0 * inv + bias[c0];
    o.y = acc1 * inv + bias[c0 + 1];
    *(float2*)(outp + (size_t)node * 64 + c0) = o;
}

extern "C" void kernel_launch(void* const* d_in, const int* in_sizes, int n_in,
                              void* d_out, int out_size, void* d_ws, size_t ws_size,
                              hipStream_t stream) {
    const float* x   = (const float*)d_in[0];
    const int*   ei  = (const int*)d_in[1];
    const float* W0  = (const float*)d_in[2];
    const float* as0 = (const float*)d_in[3];
    const float* ad0 = (const float*)d_in[4];
    const float* b0  = (const float*)d_in[5];
    const float* W1  = (const float*)d_in[6];
    const float* as1 = (const float*)d_in[7];
    const float* ad1 = (const float*)d_in[8];
    const float* b1  = (const float*)d_in[9];
    const float* W2  = (const float*)d_in[10];
    const float* as2 = (const float*)d_in[11];
    const float* ad2 = (const float*)d_in[12];
    const float* b2  = (const float*)d_in[13];
    float* out = (float*)d_out;

    const int n = in_sizes[0] / 128;   // 50000
    const int E = in_sizes[1] / 2;     // 800000
    const int* esrc = ei;
    const int* edst = ei + E;

    // workspace (~58 MB)
    char* ws = (char*)d_ws;
    bf16* hb0 = (bf16*)ws;                                   // n*256 bf16
    bf16* hb1 = hb0 + (size_t)n * 256;                       // n*256 bf16
    bf16* xb  = hb1 + (size_t)n * 256;                       // n*128 bf16
    bf16* wt0 = xb + (size_t)n * 128;                        // 256*128
    bf16* wt1 = wt0 + 128 * 256;                             // 256*256
    bf16* wt2 = wt1 + 256 * 256;                             // 64*256
    float* asb = (float*)(wt2 + 256 * 64);                   // n*4 fp32
    float* adb = asb + (size_t)n * 4;                        // n*4 fp32
    int* row_ptr = (int*)(adb + (size_t)n * 4);              // n+1 (+pad)
    int* cursor  = row_ptr + (n + 64);                       // n  (doubles as counts)
    int* col_src = cursor + n;                               // E+n
    int* blocksums = col_src + (E + n + 64);                 // <=64

    const int nb = (n + 1023) / 1024;  // 49 scan blocks
    const int nc4 = n * 128 / 4;       // x convert quads

    // ---- one-time prep (1 dispatch) + CSR build (4 dispatches) — r12 proven chain ----
    int prep_threads = nc4 + 114688 + n;
    prep_kernel<<<(prep_threads + 255) / 256, 256, 0, stream>>>(
        x, xb, nc4, W0, W1, W2, wt0, wt1, wt2, cursor, n);
    hist_kernel<<<(E + 255) / 256, 256, 0, stream>>>(edst, cursor, E, n);
    scan_phase1<<<nb, 1024, 0, stream>>>(cursor, row_ptr, blocksums, n);
    scan_phase2<<<nb, 1024, 0, stream>>>(blocksums, row_ptr, cursor, nb, n);
    scatter_kernel<<<(E + n + 255) / 256, 256, 0, stream>>>(esrc, edst, cursor, col_src, E, n);

    dim3 blk(256);
    int mg128 = (n + 127) / 128;
    int mg64  = (n + 63) / 64;
    int ag4 = (n + 3) / 4;             // wave per node
    int ag4s = ((n + 31) / 32) * 8;    // 8 slices x 32 nodes/block
    int ag2 = (n + 7) / 8;             // half-wave per node

    // ---- layer 0: x[n,128] @ W0[128,256]; agg = XCD-sliced EXPERIMENT ----
    gemm128_kernel<<<dim3(mg128, 2), blk, 0, stream>>>(xb, wt0, hb0, as0, ad0,
                                                       asb, adb, n, 128, 256, 4);
    agg4s_kernel<<<ag4s, blk, 0, stream>>>(hb0, asb, adb, row_ptr, col_src, b0, hb1, n);
    // ---- layer 1: h[n,256] @ W1[256,256]; agg = r12 CONTROL ----
    gemm128_kernel<<<dim3(mg128, 2), blk, 0, stream>>>(hb1, wt1, hb0, as1, ad1,
                                                       asb, adb, n, 256, 256, 4);
    agg4_kernel<<<ag4, blk, 0, stream>>>(hb0, asb, adb, row_ptr, col_src, b1, hb1, n);
    // ---- layer 2: h[n,256] @ W2[256,64], heads=1, no ELU, fp32 out ----
    gemm64_kernel<<<dim3(mg64, 1), blk, 0, stream>>>(hb1, wt2, hb0, as2, ad2,
                                                     asb, adb, n, 256, 64);
    agg2_kernel<<<ag2, blk, 0, stream>>>(hb0, asb, adb, row_ptr, col_src, b2, out, n);
}

// Round 15
// 398.959 us; speedup vs baseline: 1.3859x; 1.1300x over previous
//
#include <hip/hip_runtime.h>
#include <hip/hip_bf16.h>

typedef __hip_bfloat16 bf16;
typedef short s8v __attribute__((ext_vector_type(8)));   // 8 bf16 (4 VGPRs)
typedef float f32x4 __attribute__((ext_vector_type(4))); // MFMA accumulator

__device__ __forceinline__ unsigned short f2bf_bits(float x) {
    union { bf16 h; unsigned short u; } v; v.h = __float2bfloat16(x); return v.u;
}
__device__ __forceinline__ float bfbits2f(unsigned short u) {
    union { unsigned u32; float f; } v; v.u32 = ((unsigned)u) << 16; return v.f;
}

// async global->LDS, 16B per lane; LDS dest must be uniform base + lane*16
template<typename T>
__device__ __forceinline__ void gload_lds16(const T* g, T* l) {
    __builtin_amdgcn_global_load_lds(
        (const __attribute__((address_space(1))) unsigned int*)g,
        (__attribute__((address_space(3))) unsigned int*)l, 16, 0, 0);
}

__device__ __forceinline__ uint4 load8(const bf16* p) { return *(const uint4*)p; }

// ---------------- prep + histogram (cursor pre-zeroed by memset) ----------------
__device__ __forceinline__ void tr1(const float* W, bf16* Wt, int idx, int K, int N) {
    int nn = idx / K, k = idx - nn * K;
    Wt[idx] = __float2bfloat16(W[(size_t)k * N + nn]);
}
__global__ void prep_hist_kernel(const float* __restrict__ x, bf16* __restrict__ xb, int nc4,
                                 const float* __restrict__ W0, const float* __restrict__ W1,
                                 const float* __restrict__ W2, bf16* __restrict__ wt0,
                                 bf16* __restrict__ wt1, bf16* __restrict__ wt2,
                                 const int* __restrict__ edst, int* __restrict__ cursor,
                                 int E, int n) {
    int idx = blockIdx.x * blockDim.x + threadIdx.x;
    if (idx < nc4) {
        float4 f = *(const float4*)(x + (size_t)idx * 4);
        union { uint2 u; unsigned short us[4]; } cv;
        cv.us[0] = f2bf_bits(f.x); cv.us[1] = f2bf_bits(f.y);
        cv.us[2] = f2bf_bits(f.z); cv.us[3] = f2bf_bits(f.w);
        *(uint2*)(xb + (size_t)idx * 4) = cv.u;
        return;
    }
    int i2 = idx - nc4;
    if (i2 < 32768) { tr1(W0, wt0, i2, 128, 256); return; }
    i2 -= 32768;
    if (i2 < 65536) { tr1(W1, wt1, i2, 256, 256); return; }
    i2 -= 65536;
    if (i2 < 16384) { tr1(W2, wt2, i2, 256, 64); return; }
    i2 -= 16384;
    if (i2 < E) {
        int d = edst[i2];
        if ((unsigned)d < (unsigned)n) atomicAdd(&cursor[d], 1);
    }
}

// hierarchical scan, phase 1: per-block (1024) local exclusive scan of counts[i]+1
__global__ __launch_bounds__(1024) void scan_phase1(
        const int* __restrict__ counts, int* __restrict__ excl_out,
        int* __restrict__ blocksums, int n) {
    __shared__ int wsum[16];
    __shared__ int woff[16];
    int tid = threadIdx.x, lane = tid & 63, wid = tid >> 6;
    int i = blockIdx.x * 1024 + tid;
    int v = (i < n) ? counts[i] + 1 : 0;   // +1 = self-loop
    int incl = v;
    #pragma unroll
    for (int d = 1; d < 64; d <<= 1) {
        int t = __shfl_up(incl, d, 64);
        if (lane >= d) incl += t;
    }
    if (lane == 63) wsum[wid] = incl;
    __syncthreads();
    if (wid == 0) {
        int wv = (lane < 16) ? wsum[lane] : 0;
        int wincl = wv;
        #pragma unroll
        for (int d = 1; d < 16; d <<= 1) {
            int t = __shfl_up(wincl, d, 64);
            if (lane >= d) wincl += t;
        }
        if (lane < 16) woff[lane] = wincl - wv;
    }
    __syncthreads();
    if (i < n) excl_out[i] = woff[wid] + incl - v;
    if (tid == 1023) blocksums[blockIdx.x] = woff[15] + wsum[15];
}

// phase 2: every wave redundantly scans the <=64 block sums; apply offsets
__global__ __launch_bounds__(1024) void scan_phase2(
        const int* __restrict__ blocksums, int* __restrict__ row_ptr,
        int* __restrict__ cursor, int nb, int n) {
    int tid = threadIdx.x, lane = tid & 63;
    int i = blockIdx.x * 1024 + tid;
    int v = (lane < nb) ? blocksums[lane] : 0;
    int incl = v;
    #pragma unroll
    for (int d = 1; d < 64; d <<= 1) {
        int t = __shfl_up(incl, d, 64);
        if (lane >= d) incl += t;
    }
    int excl_lane = incl - v;
    int base = __shfl(excl_lane, blockIdx.x, 64);
    int total = __shfl(incl, nb - 1, 64);
    if (i < n) {
        int val = row_ptr[i] + base;
        row_ptr[i] = val;
        cursor[i] = val;
    }
    if (blockIdx.x == 0 && tid == 0) row_ptr[n] = total;
}

// ---------------- 128x128 MFMA GEMM body + fused alpha epilogue (direct store) --------
__device__ __forceinline__ void gemm128_body(
        const bf16* __restrict__ A, const bf16* __restrict__ Wt, bf16* __restrict__ C,
        const float* __restrict__ a_src, const float* __restrict__ a_dst,
        float* __restrict__ asb, float* __restrict__ adb,
        int M, int K, int N, int H, int m_tile, int n_tile,
        bf16* As, bf16* Bs) {
    int tid = threadIdx.x;
    int w = tid >> 6, l = tid & 63;
    int lm = l & 15, quad = l >> 4;
    int m0 = m_tile * 128, n0 = n_tile * 128;
    int wr = (w >> 1) * 64, wc = (w & 1) * 64;
    int srow = w * 32 + (l >> 3);
    int schunk = l & 7;
    f32x4 acc[4][4] = {};
    for (int kt = 0; kt < K; kt += 64) {
        #pragma unroll
        for (int j = 0; j < 4; ++j) {
            int row = srow + j * 8;
            int g = schunk ^ (row & 7);
            int m = m0 + row; if (m >= M) m = M - 1;  // clamp: dup rows, never stored
            gload_lds16(A + (size_t)m * K + kt + g * 8, As + row * 64 + schunk * 8);
            gload_lds16(Wt + (size_t)(n0 + row) * K + kt + g * 8, Bs + row * 64 + schunk * 8);
        }
        __syncthreads();
        #pragma unroll
        for (int ks = 0; ks < 2; ++ks) {
            s8v a[4], b[4];
            #pragma unroll
            for (int mi = 0; mi < 4; ++mi) {
                int row = wr + mi * 16 + lm;
                int c = (ks * 4 + quad) ^ (row & 7);
                a[mi] = *(const s8v*)(As + row * 64 + c * 8);
            }
            #pragma unroll
            for (int ni = 0; ni < 4; ++ni) {
                int row = wc + ni * 16 + lm;
                int c = (ks * 4 + quad) ^ (row & 7);
                b[ni] = *(const s8v*)(Bs + row * 64 + c * 8);
            }
            #pragma unroll
            for (int mi = 0; mi < 4; ++mi)
                #pragma unroll
                for (int ni = 0; ni < 4; ++ni)
                    acc[mi][ni] = __builtin_amdgcn_mfma_f32_16x16x32_bf16(
                        a[mi], b[ni], acc[mi][ni], 0, 0, 0);
        }
        __syncthreads();
    }
    int head = (n0 + wc) >> 6;
    float a_s[4], a_d[4];
    #pragma unroll
    for (int ni = 0; ni < 4; ++ni) {
        int col = n0 + wc + ni * 16 + lm;
        a_s[ni] = a_src[col];
        a_d[ni] = a_dst[col];
    }
    #pragma unroll
    for (int mi = 0; mi < 4; ++mi) {
        #pragma unroll
        for (int reg = 0; reg < 4; ++reg) {
            int m = m0 + wr + mi * 16 + quad * 4 + reg;
            float ps = 0.f, pd = 0.f;
            #pragma unroll
            for (int ni = 0; ni < 4; ++ni) {
                float v = acc[mi][ni][reg];
                ps += v * a_s[ni];
                pd += v * a_d[ni];
                if (m < M)
                    C[(size_t)m * N + n0 + wc + ni * 16 + lm] = __float2bfloat16(v);
            }
            #pragma unroll
            for (int d = 1; d < 16; d <<= 1) {
                ps += __shfl_xor(ps, d, 64);
                pd += __shfl_xor(pd, d, 64);
            }
            if (lm == 0 && m < M) {
                asb[(size_t)m * H + head] = ps;
                adb[(size_t)m * H + head] = pd;
            }
        }
    }
}

__global__ __launch_bounds__(256) void gemm128_kernel(
        const bf16* __restrict__ A, const bf16* __restrict__ Wt, bf16* __restrict__ C,
        const float* __restrict__ a_src, const float* __restrict__ a_dst,
        float* __restrict__ asb, float* __restrict__ adb,
        int M, int K, int N, int H) {
    __shared__ __align__(16) bf16 As[128 * 64];
    __shared__ __align__(16) bf16 Bs[128 * 64];
    gemm128_body(A, Wt, C, a_src, a_dst, asb, adb, M, K, N, H,
                 blockIdx.x, blockIdx.y, As, Bs);
}

// ---------------- fused: layer-0 GEMM + edge scatter (independent workloads) --------
// Blocks [0, ngemm) run the gemm; blocks [ngemm, ...) scatter edges into CSR.
// Disjoint R/W sets: gemm reads xb/wt0 writes hb0/asb/adb; scatter reads ei,
// read-modify-writes cursor, writes col_src.
__global__ __launch_bounds__(256) void gemm0_scatter_kernel(
        const bf16* __restrict__ A, const bf16* __restrict__ Wt, bf16* __restrict__ C,
        const float* __restrict__ a_src, const float* __restrict__ a_dst,
        float* __restrict__ asb, float* __restrict__ adb,
        int M, int K, int N, int H, int ngemm,
        const int* __restrict__ esrc, const int* __restrict__ edst,
        int* __restrict__ cursor, int* __restrict__ col_src, int E, int n) {
    __shared__ __align__(16) bf16 As[128 * 64];
    __shared__ __align__(16) bf16 Bs[128 * 64];
    int bx = blockIdx.x;
    if (bx < ngemm) {
        gemm128_body(A, Wt, C, a_src, a_dst, asb, adb, M, K, N, H,
                     bx >> 1, bx & 1, As, Bs);
        return;
    }
    int i = (bx - ngemm) * 256 + threadIdx.x;
    if (i < E) {
        int d = edst[i];
        if ((unsigned)d >= (unsigned)n) return;
        int s = esrc[i];
        if ((unsigned)s >= (unsigned)n) s = d;
        int pos = atomicAdd(&cursor[d], 1);
        col_src[pos] = s;
    } else if (i < E + n) {
        int v = i - E;
        int pos = atomicAdd(&cursor[v], 1);
        col_src[pos] = v;  // self-loop
    }
}

// ---------------- 64x64 MFMA GEMM + fused alpha (layer 2, N=64, H=1, direct store) ----
__global__ __launch_bounds__(256) void gemm64_kernel(
        const bf16* __restrict__ A, const bf16* __restrict__ Wt, bf16* __restrict__ C,
        const float* __restrict__ a_src, const float* __restrict__ a_dst,
        float* __restrict__ asb, float* __restrict__ adb,
        int M, int K, int N) {
    __shared__ __align__(16) bf16 As[64][72];
    __shared__ __align__(16) bf16 Bs[64][72];
    int tid = threadIdx.x;
    int m0 = blockIdx.x * 64;
    int w = tid >> 6;
    int l = tid & 63;
    int lm = l & 15;
    int quad = l >> 4;
    int r = tid >> 2;
    int kb = (tid & 3) * 8;
    f32x4 acc[4] = {};
    int mstage = m0 + r;
    for (int kt = 0; kt < K; kt += 64) {
        #pragma unroll
        for (int c = 0; c < 2; ++c) {
            int kk = kb + c * 32;
            uint4 av = (mstage < M) ? load8(&A[(size_t)mstage * K + kt + kk])
                                    : make_uint4(0, 0, 0, 0);
            *(uint4*)&As[r][kk] = av;
            *(uint4*)&Bs[r][kk] = load8(&Wt[(size_t)r * K + kt + kk]);
        }
        __syncthreads();
        #pragma unroll
        for (int ks = 0; ks < 2; ++ks) {
            s8v a = *(const s8v*)&As[w * 16 + lm][ks * 32 + quad * 8];
            #pragma unroll
            for (int nb = 0; nb < 4; ++nb) {
                s8v b = *(const s8v*)&Bs[nb * 16 + lm][ks * 32 + quad * 8];
                acc[nb] = __builtin_amdgcn_mfma_f32_16x16x32_bf16(a, b, acc[nb], 0, 0, 0);
            }
        }
        __syncthreads();
    }
    float a_s[4], a_d[4];
    #pragma unroll
    for (int nb = 0; nb < 4; ++nb) {
        a_s[nb] = a_src[nb * 16 + lm];
        a_d[nb] = a_dst[nb * 16 + lm];
    }
    #pragma unroll
    for (int reg = 0; reg < 4; ++reg) {
        int m = m0 + w * 16 + quad * 4 + reg;
        float ps = 0.f, pd = 0.f;
        #pragma unroll
        for (int nb = 0; nb < 4; ++nb) {
            float v = acc[nb][reg];
            ps += v * a_s[nb];
            pd += v * a_d[nb];
            if (m < M)
                C[(size_t)m * N + nb * 16 + lm] = __float2bfloat16(v);
        }
        #pragma unroll
        for (int d = 1; d < 16; d <<= 1) {
            ps += __shfl_xor(ps, d, 64);
            pd += __shfl_xor(pd, d, 64);
        }
        if (lm == 0 && m < M) {
            asb[m] = ps;
            adb[m] = pd;
        }
    }
}

// ---------------- 4-head edge softmax + aggregation (r12 proven form) ----------------
__global__ __launch_bounds__(256) void agg4_kernel(
        const bf16* __restrict__ hbuf,
        const float* __restrict__ asb, const float* __restrict__ adb,
        const int* __restrict__ row_ptr, const int* __restrict__ col_src,
        const float* __restrict__ bias,
        bf16* __restrict__ outp, int n) {
    int lane = threadIdx.x & 63;
    int node = blockIdx.x * 4 + (threadIdx.x >> 6);
    if (node >= n) return;
    const int c0 = lane * 4;
    const int head = c0 >> 6;
    int start = row_ptr[node], end = row_ptr[node + 1];
    float adn = adb[(size_t)node * 4 + head];
    float acc[4] = {};
    float denom = 0.f;

    auto edge_w = [&](int s) -> float {
        float x = asb[(size_t)s * 4 + head] + adn;
        x = (x > 0.f) ? x : 0.2f * x;            // leaky_relu 0.2
        return __expf(fminf(x, 30.f));
    };
    auto loadH = [&](int s, float* o) {
        union { uint2 u; unsigned short us[4]; } cv;
        cv.u = *(const uint2*)(hbuf + (size_t)s * 256 + c0);
        #pragma unroll
        for (int v = 0; v < 4; ++v) o[v] = bfbits2f(cv.us[v]);
    };

    int e = start;
    for (; e + 4 <= end; e += 4) {
        int s0 = col_src[e], s1 = col_src[e + 1], s2 = col_src[e + 2], s3 = col_src[e + 3];
        float h0[4], h1[4], h2[4], h3[4];
        loadH(s0, h0); loadH(s1, h1); loadH(s2, h2); loadH(s3, h3);
        float w0 = edge_w(s0), w1 = edge_w(s1), w2 = edge_w(s2), w3 = edge_w(s3);
        denom += (w0 + w1) + (w2 + w3);
        #pragma unroll
        for (int v = 0; v < 4; ++v)
            acc[v] += w0 * h0[v] + w1 * h1[v] + w2 * h2[v] + w3 * h3[v];
    }
    for (; e < end; ++e) {
        int s = col_src[e];
        float hv[4];
        loadH(s, hv);
        float w = edge_w(s);
        denom += w;
        #pragma unroll
        for (int v = 0; v < 4; ++v) acc[v] += w * hv[v];
    }
    float inv = 1.f / (denom + 1e-16f);
    union { uint2 u; unsigned short us[4]; } cv;
    #pragma unroll
    for (int v = 0; v < 4; ++v) {
        float o = acc[v] * inv + bias[c0 + v];
        o = (o > 0.f) ? o : (__expf(o) - 1.f);   // ELU
        cv.us[v] = f2bf_bits(o);
    }
    *(uint2*)(outp + (size_t)node * 256 + c0) = cv.u;
}

// ---------------- layer-2 aggregation: 2 nodes per wave (half-wave, VEC=2) ----------
__global__ __launch_bounds__(256) void agg2_kernel(
        const bf16* __restrict__ hbuf,
        const float* __restrict__ asb, const float* __restrict__ adb,
        const int* __restrict__ row_ptr, const int* __restrict__ col_src,
        const float* __restrict__ bias,
        float* __restrict__ outp, int n) {
    int tid = threadIdx.x;
    int l32 = tid & 31;
    int node = blockIdx.x * 8 + (tid >> 5);   // 8 nodes per 256-thread block
    if (node >= n) return;
    const int c0 = l32 * 2;
    int start = row_ptr[node], end = row_ptr[node + 1];
    float adn = adb[node];
    float acc0 = 0.f, acc1 = 0.f, denom = 0.f;

    auto edge_w = [&](int s) -> float {
        float x = asb[s] + adn;
        x = (x > 0.f) ? x : 0.2f * x;
        return __expf(fminf(x, 30.f));
    };
    auto loadH2 = [&](int s, float& o0, float& o1) {
        unsigned u = *(const unsigned*)(hbuf + (size_t)s * 64 + c0);
        o0 = bfbits2f((unsigned short)(u & 0xffffu));
        o1 = bfbits2f((unsigned short)(u >> 16));
    };

    int e = start;
    for (; e + 4 <= end; e += 4) {
        int s0 = col_src[e], s1 = col_src[e + 1], s2 = col_src[e + 2], s3 = col_src[e + 3];
        float a0, b0, a1, b1, a2, b2, a3, b3;
        loadH2(s0, a0, b0); loadH2(s1, a1, b1); loadH2(s2, a2, b2); loadH2(s3, a3, b3);
        float w0 = edge_w(s0), w1 = edge_w(s1), w2 = edge_w(s2), w3 = edge_w(s3);
        denom += (w0 + w1) + (w2 + w3);
        acc0 += w0 * a0 + w1 * a1 + w2 * a2 + w3 * a3;
        acc1 += w0 * b0 + w1 * b1 + w2 * b2 + w3 * b3;
    }
    for (; e < end; ++e) {
        int s = col_src[e];
        float a, b;
        loadH2(s, a, b);
        float w = edge_w(s);
        denom += w;
        acc0 += w * a;
        acc1 += w * b;
    }
    float inv = 1.f / (denom + 1e-16f);
    float2 o;
    o.x = acc0 * inv + bias[c0];
    o.y = acc1 * inv + bias[c0 + 1];
    *(float2*)(outp + (size_t)node * 64 + c0) = o;
}

extern "C" void kernel_launch(void* const* d_in, const int* in_sizes, int n_in,
                              void* d_out, int out_size, void* d_ws, size_t ws_size,
                              hipStream_t stream) {
    const float* x   = (const float*)d_in[0];
    const int*   ei  = (const int*)d_in[1];
    const float* W0  = (const float*)d_in[2];
    const float* as0 = (const float*)d_in[3];
    const float* ad0 = (const float*)d_in[4];
    const float* b0  = (const float*)d_in[5];
    const float* W1  = (const float*)d_in[6];
    const float* as1 = (const float*)d_in[7];
    const float* ad1 = (const float*)d_in[8];
    const float* b1  = (const float*)d_in[9];
    const float* W2  = (const float*)d_in[10];
    const float* as2 = (const float*)d_in[11];
    const float* ad2 = (const float*)d_in[12];
    const float* b2  = (const float*)d_in[13];
    float* out = (float*)d_out;

    const int n = in_sizes[0] / 128;   // 50000
    const int E = in_sizes[1] / 2;     // 800000
    const int* esrc = ei;
    const int* edst = ei + E;

    // workspace (~58 MB)
    char* ws = (char*)d_ws;
    bf16* hb0 = (bf16*)ws;                                   // n*256 bf16
    bf16* hb1 = hb0 + (size_t)n * 256;                       // n*256 bf16
    bf16* xb  = hb1 + (size_t)n * 256;                       // n*128 bf16
    bf16* wt0 = xb + (size_t)n * 128;                        // 256*128
    bf16* wt1 = wt0 + 128 * 256;                             // 256*256
    bf16* wt2 = wt1 + 256 * 256;                             // 64*256
    float* asb = (float*)(wt2 + 256 * 64);                   // n*4 fp32
    float* adb = asb + (size_t)n * 4;                        // n*4 fp32
    int* row_ptr = (int*)(adb + (size_t)n * 4);              // n+1 (+pad)
    int* cursor  = row_ptr + (n + 64);                       // n  (doubles as counts)
    int* col_src = cursor + n;                               // E+n
    int* blocksums = col_src + (E + n + 64);                 // <=64

    const int nb = (n + 1023) / 1024;  // 49 scan blocks
    const int nc4 = n * 128 / 4;       // x convert quads

    // ---- build: memset + prep+hist + scan1 + scan2 (scatter fused into gemm0) ----
    hipMemsetAsync(cursor, 0, (size_t)n * sizeof(int), stream);
    int ph_threads = nc4 + 114688 + E;
    prep_hist_kernel<<<(ph_threads + 255) / 256, 256, 0, stream>>>(
        x, xb, nc4, W0, W1, W2, wt0, wt1, wt2, edst, cursor, E, n);
    scan_phase1<<<nb, 1024, 0, stream>>>(cursor, row_ptr, blocksums, n);
    scan_phase2<<<nb, 1024, 0, stream>>>(blocksums, row_ptr, cursor, nb, n);

    dim3 blk(256);
    int mg128 = (n + 127) / 128;
    int mg64  = (n + 63) / 64;
    int ag4 = (n + 3) / 4;             // wave per node
    int ag2 = (n + 7) / 8;             // half-wave per node
    int ngemm = mg128 * 2;
    int nscat = (E + n + 255) / 256;

    // ---- layer 0: gemm (xb @ W0) fused with CSR scatter (independent) ----
    gemm0_scatter_kernel<<<ngemm + nscat, blk, 0, stream>>>(
        xb, wt0, hb0, as0, ad0, asb, adb, n, 128, 256, 4, ngemm,
        esrc, edst, cursor, col_src, E, n);
    agg4_kernel<<<ag4, blk, 0, stream>>>(hb0, asb, adb, row_ptr, col_src, b0, hb1, n);
    // ---- layer 1: h[n,256] @ W1[256,256] ----
    gemm128_kernel<<<dim3(mg128, 2), blk, 0, stream>>>(hb1, wt1, hb0, as1, ad1,
                                                       asb, adb, n, 256, 256, 4);
    agg4_kernel<<<ag4, blk, 0, stream>>>(hb0, asb, adb, row_ptr, col_src, b1, hb1, n);
    // ---- layer 2: h[n,256] @ W2[256,64], heads=1, no ELU, fp32 out ----
    gemm64_kernel<<<mg64, blk, 0, stream>>>(hb1, wt2, hb0, as2, ad2,
                                            asb, adb, n, 256, 64);
    agg2_kernel<<<ag2, blk, 0, stream>>>(hb0, asb, adb, row_ptr, col_src, b2, out, n);
}